// Round 4
// baseline (184.271 us; speedup 1.0000x reference)
//
#include <hip/hip_runtime.h>

// in : 2 planes (re, im) of [2048, 8, 8, 64] float32  (67 MB read)
// out: [2, 2048, 8, 16, 64] float32                   (134 MB write)
// Block b even -> qubit 0 (mask 32, half-split sign); odd -> qubit 5 (mask 1,
// alternating sign).
//   out[b, d,    i] = S * in[b, d, i ^ m]                       S = 2^-0.25
//   out[b, d+8,  i] = sigma(i) * K * ((re-im) + (re+im) i)      K = 2^-0.75

#define P_STRIDE     (2048 * 8 * 16 * 64)   // floats per output plane
#define VEC_PER_PASS (2048 * 256)           // float4s handled per grid pass
#define PASS_OFF     (512 * 8192)           // float offset advance per pass
#define N_PASS       4                      // TOTAL_VEC / VEC_PER_PASS

// clang-native 4-float vector: __builtin_nontemporal_store requires a native
// vector type, not HIP's HIP_vector_type<float,4> class.
typedef float vfloat4 __attribute__((ext_vector_type(4)));

__device__ __forceinline__ void nt_store4(float* p, float x, float y, float z, float w) {
    vfloat4 v = {x, y, z, w};
    __builtin_nontemporal_store(v, reinterpret_cast<vfloat4*>(p));
}

__global__ __launch_bounds__(256) void entangle_kernel(
    const float4* __restrict__ in_re,
    const float4* __restrict__ in_im,
    float*        __restrict__ out)
{
    const float S = 0.84089641525371454f;  // 2^-0.25
    const float K = 0.59460355750136051f;  // 2^-0.75

    const int v0     = blockIdx.x * blockDim.x + threadIdx.x;  // < VEC_PER_PASS
    const int i4     = v0 & 15;
    const int d      = (v0 >> 4) & 7;
    const int blk    = (v0 >> 7) & 7;     // wave-uniform (64 consecutive v share it)
    const int batch0 = v0 >> 10;
    const bool even_blk = (blk & 1) == 0;

    const int base    = batch0 * 8192 + blk * 1024;
    const int top_col = even_blk ? ((i4 * 4) ^ 32) : (i4 * 4);
    int top_off = base + d * 64 + top_col;
    int bot_off = base + (d + 8) * 64 + i4 * 4;
    int vin     = v0;
    // sign for the bottom half, even-block case (uniform across the float4)
    const float ke = (i4 < 8) ? K : -K;

#pragma unroll
    for (int it = 0; it < N_PASS; ++it) {
        float4 a = in_re[vin];
        float4 b = in_im[vin];

        if (even_blk) {
            nt_store4(out + top_off,            S * a.x, S * a.y, S * a.z, S * a.w);
            nt_store4(out + P_STRIDE + top_off, S * b.x, S * b.y, S * b.z, S * b.w);
            nt_store4(out + bot_off,
                      ke * (a.x - b.x), ke * (a.y - b.y),
                      ke * (a.z - b.z), ke * (a.w - b.w));
            nt_store4(out + P_STRIDE + bot_off,
                      ke * (a.x + b.x), ke * (a.y + b.y),
                      ke * (a.z + b.z), ke * (a.w + b.w));
        } else {
            // mask 1: lane swap within the float4; sign alternates +,-,+,-
            nt_store4(out + top_off,            S * a.y, S * a.x, S * a.w, S * a.z);
            nt_store4(out + P_STRIDE + top_off, S * b.y, S * b.x, S * b.w, S * b.z);
            nt_store4(out + bot_off,
                       K * (a.x - b.x), -K * (a.y - b.y),
                       K * (a.z - b.z), -K * (a.w - b.w));
            nt_store4(out + P_STRIDE + bot_off,
                       K * (a.x + b.x), -K * (a.y + b.y),
                       K * (a.z + b.z), -K * (a.w + b.w));
        }

        vin     += VEC_PER_PASS;
        top_off += PASS_OFF;
        bot_off += PASS_OFF;
    }
}

extern "C" void kernel_launch(void* const* d_in, const int* in_sizes, int n_in,
                              void* d_out, int out_size, void* d_ws, size_t ws_size,
                              hipStream_t stream) {
    const float4* in_re = reinterpret_cast<const float4*>(d_in[0]);
    const float4* in_im = reinterpret_cast<const float4*>(d_in[1]);
    float* out = reinterpret_cast<float*>(d_out);

    // Exactly VEC_PER_PASS threads; each does N_PASS fully-unrolled passes.
    entangle_kernel<<<dim3(2048), dim3(256), 0, stream>>>(in_re, in_im, out);
}